// Round 1
// baseline (4387.730 us; speedup 1.0000x reference)
//
#include <hip/hip_runtime.h>
#include <math.h>

constexpr int Bn = 8;
constexpr int Np = 2048;
constexpr int Kn = 32;
constexpr float NEGS = 0.2f;

__device__ __forceinline__ unsigned fenc(float f) {
    unsigned u = __float_as_uint(f);
    return (u & 0x80000000u) ? ~u : (u | 0x80000000u);
}
__device__ __forceinline__ float fdec(unsigned u) {
    return (u & 0x80000000u) ? __uint_as_float(u & 0x7fffffffu) : __uint_as_float(~u);
}
__device__ __forceinline__ float lrelu(float v) { return v > 0.f ? v : NEGS * v; }

// x [B,3,N] -> pts point-major [B*N, 4] (pad lane = 0)
__global__ __launch_bounds__(256) void k_transpose(const float* __restrict__ x, float* __restrict__ pts) {
    int i = blockIdx.x * 256 + threadIdx.x;
    int b = i / Np, n = i % Np;
    float p0 = x[((size_t)b * 3 + 0) * Np + n];
    float p1 = x[((size_t)b * 3 + 1) * Np + n];
    float p2 = x[((size_t)b * 3 + 2) * Np + n];
    float4 v = make_float4(p0, p1, p2, 0.f);
    *(float4*)&pts[(size_t)i * 4] = v;
}

// xx[i] = sum_c pm[i*ld+c]^2 ; one wave per point, 4 points per block
__global__ __launch_bounds__(256) void k_xx(const float* __restrict__ pm, float* __restrict__ xxg, int C, int ld) {
    int wid = threadIdx.x >> 6, lane = threadIdx.x & 63;
    int pt = blockIdx.x * 4 + wid;
    const float* row = pm + (size_t)pt * ld;
    float acc = 0.f;
    for (int c = lane; c < C; c += 64) { float v = row[c]; acc = fmaf(v, v, acc); }
    #pragma unroll
    for (int off = 32; off; off >>= 1) acc += __shfl_down(acc, off, 64);
    if (lane == 0) xxg[pt] = acc;
}

// kNN top-32 (largest of d = 2*inner - xx_n - xx_m). 4 rows per block.
// Distance phase: block-wide, coalesced stream of channel-major X. Selection: one wave per row, shuffle-only.
template<int C>
__global__ __launch_bounds__(256) void k_knn(const float* __restrict__ Xcm, const float* __restrict__ Xpm, int ld,
                                             const float* __restrict__ xxg, int* __restrict__ idxo) {
    __shared__ float pcs[4][C];
    __shared__ float dl[4 * Np];
    int blk = blockIdx.x;
    int b = blk / (Np / 4);
    int n0 = (blk % (Np / 4)) * 4;
    int t = threadIdx.x;
    for (int e = t; e < 4 * C; e += 256) {
        int r = e / C, c = e % C;
        pcs[r][c] = Xpm[((size_t)b * Np + n0 + r) * ld + c];
    }
    __syncthreads();
    float dot[4][8] = {};
    for (int c = 0; c < C; ++c) {
        float p0 = pcs[0][c], p1 = pcs[1][c], p2 = pcs[2][c], p3 = pcs[3][c];
        const float* xrow = Xcm + ((size_t)b * C + c) * Np;
        #pragma unroll
        for (int j = 0; j < 8; ++j) {
            float xm = xrow[t + 256 * j];
            dot[0][j] = fmaf(p0, xm, dot[0][j]);
            dot[1][j] = fmaf(p1, xm, dot[1][j]);
            dot[2][j] = fmaf(p2, xm, dot[2][j]);
            dot[3][j] = fmaf(p3, xm, dot[3][j]);
        }
    }
    float xc0 = xxg[b * Np + n0 + 0], xc1 = xxg[b * Np + n0 + 1];
    float xc2 = xxg[b * Np + n0 + 2], xc3 = xxg[b * Np + n0 + 3];
    #pragma unroll
    for (int j = 0; j < 8; ++j) {
        int m = t + 256 * j;
        float xm = xxg[b * Np + m];
        dl[0 * Np + m] = 2.f * dot[0][j] - xc0 - xm;
        dl[1 * Np + m] = 2.f * dot[1][j] - xc1 - xm;
        dl[2 * Np + m] = 2.f * dot[2][j] - xc2 - xm;
        dl[3 * Np + m] = 2.f * dot[3][j] - xc3 - xm;
    }
    __syncthreads();
    int w = t >> 6, lane = t & 63;
    float v[32];
    #pragma unroll
    for (int j = 0; j < 32; ++j) v[j] = dl[w * Np + lane + 64 * j];
    size_t ob = ((size_t)b * Np + n0 + w) * Kn;
    for (int it = 0; it < Kn; ++it) {
        float bv = v[0]; int bj = 0;
        #pragma unroll
        for (int j = 1; j < 32; ++j) if (v[j] > bv) { bv = v[j]; bj = j; }
        int bm = lane + 64 * bj;
        #pragma unroll
        for (int off = 32; off; off >>= 1) {
            float ov = __shfl_down(bv, off, 64);
            int om = __shfl_down(bm, off, 64);
            if (ov > bv || (ov == bv && om < bm)) { bv = ov; bm = om; }
        }
        bm = __shfl(bm, 0, 64);
        if ((bm & 63) == lane) v[bm >> 6] = -INFINITY;
        if (lane == 0) idxo[ob + it] = bm;
    }
}

// Fused EdgeConv: gather nbr -> LDS, h = nbr.Wn + ctr.(Wc-Wn), BN+LeakyReLU, max over k.
// Thread map: 256 = (O/OPT) * (K/KPT); each thread handles OPT outputs x KPT neighbors x PTS points.
template<int C, int CPAD, int O, int OPT, int KPT, int PTS, bool WCM>
__global__ __launch_bounds__(256) void k_edgeconv(
    const float* __restrict__ Xpm, const int* __restrict__ idxg,
    const float* __restrict__ W, const float* __restrict__ sg, const float* __restrict__ bg,
    float* __restrict__ Ypm, float* __restrict__ Ycm)
{
    constexpr int OG = O / OPT;
    constexpr int NKG = 256 / OG;
    static_assert(NKG * KPT == Kn, "k mapping");
    __shared__ float nbr[PTS][Kn][CPAD];
    __shared__ float ctr[PTS][CPAD];
    __shared__ float red[PTS][OPT][256];
    int blk = blockIdx.x;
    int b = blk / (Np / PTS);
    int n0 = (blk % (Np / PTS)) * PTS;
    int t = threadIdx.x;
    const int* ip = idxg + ((size_t)b * Np + n0) * Kn;
    for (int e = t; e < PTS * CPAD; e += 256) {
        int pt = e / CPAD, c = e % CPAD;
        ctr[pt][c] = Xpm[((size_t)b * Np + n0 + pt) * CPAD + c];
    }
    for (int e = t; e < PTS * Kn * CPAD; e += 256) {
        int pt = e / (Kn * CPAD);
        int r = e % (Kn * CPAD);
        int k = r / CPAD, c = r % CPAD;
        nbr[pt][k][c] = Xpm[((size_t)b * Np + ip[pt * Kn + k]) * CPAD + c];
    }
    __syncthreads();
    int og = t % OG, kg = t / OG;
    float ctt[PTS][OPT] = {};
    for (int c = 0; c < C; ++c) {
        #pragma unroll
        for (int p = 0; p < OPT; ++p) {
            const float* wr = W + (size_t)(og + p * OG) * (2 * C);
            float wd = wr[C + c] - wr[c];
            #pragma unroll
            for (int pt = 0; pt < PTS; ++pt) ctt[pt][p] = fmaf(wd, ctr[pt][c], ctt[pt][p]);
        }
    }
    float acc[PTS][OPT][KPT] = {};
    for (int c0 = 0; c0 < CPAD; c0 += 4) {
        float wv[OPT][4];
        #pragma unroll
        for (int p = 0; p < OPT; ++p) {
            #pragma unroll
            for (int cc = 0; cc < 4; ++cc) {
                int c = c0 + cc;
                wv[p][cc] = (c < C) ? W[(size_t)(og + p * OG) * (2 * C) + c] : 0.f;
            }
        }
        #pragma unroll
        for (int pt = 0; pt < PTS; ++pt) {
            #pragma unroll
            for (int k = 0; k < KPT; ++k) {
                const float* nb = &nbr[pt][kg * KPT + k][c0];
                float q0 = nb[0], q1 = nb[1], q2 = nb[2], q3 = nb[3];
                #pragma unroll
                for (int p = 0; p < OPT; ++p) {
                    acc[pt][p][k] = fmaf(wv[p][0], q0, acc[pt][p][k]);
                    acc[pt][p][k] = fmaf(wv[p][1], q1, acc[pt][p][k]);
                    acc[pt][p][k] = fmaf(wv[p][2], q2, acc[pt][p][k]);
                    acc[pt][p][k] = fmaf(wv[p][3], q3, acc[pt][p][k]);
                }
            }
        }
    }
    #pragma unroll
    for (int pt = 0; pt < PTS; ++pt) {
        #pragma unroll
        for (int p = 0; p < OPT; ++p) {
            int o = og + p * OG;
            float sv = sg[o], bv = bg[o];
            float m = -INFINITY;
            #pragma unroll
            for (int k = 0; k < KPT; ++k) {
                float hv = fmaf(acc[pt][p][k] + ctt[pt][p], sv, bv);
                m = fmaxf(m, lrelu(hv));
            }
            red[pt][p][t] = m;
        }
    }
    __syncthreads();
    if (kg == 0) {
        #pragma unroll
        for (int pt = 0; pt < PTS; ++pt) {
            #pragma unroll
            for (int p = 0; p < OPT; ++p) {
                float m = red[pt][p][og];
                #pragma unroll
                for (int j = 1; j < NKG; ++j) m = fmaxf(m, red[pt][p][j * OG + og]);
                int o = og + p * OG;
                Ypm[((size_t)b * Np + n0 + pt) * O + o] = m;
                if (WCM) Ycm[((size_t)b * O + o) * Np + n0 + pt] = m;
            }
        }
    }
}

// W5 (1024x512) + BN + LeakyReLU + fused global max/sum pooling via atomics. 8 points per block.
__global__ __launch_bounds__(256) void k_w5pool(
    const float* __restrict__ x1, const float* __restrict__ x2,
    const float* __restrict__ x3, const float* __restrict__ x4,
    const float* __restrict__ W5, const float* __restrict__ s5, const float* __restrict__ b5,
    unsigned* __restrict__ gmax, float* __restrict__ gsum)
{
    constexpr int PTS = 8;
    __shared__ float cat[PTS][512];
    int blk = blockIdx.x;
    int b = blk / (Np / PTS);
    int n0 = (blk % (Np / PTS)) * PTS;
    int t = threadIdx.x;
    for (int e = t; e < PTS * 512; e += 256) {
        int pt = e >> 9, c = e & 511;
        size_t pi = (size_t)b * Np + n0 + pt;
        float v;
        if (c < 64)       v = x1[pi * 64 + c];
        else if (c < 128) v = x2[pi * 64 + (c - 64)];
        else if (c < 256) v = x3[pi * 128 + (c - 128)];
        else              v = x4[pi * 256 + (c - 256)];
        cat[pt][c] = v;
    }
    __syncthreads();
    float acc[4][PTS] = {};
    for (int c0 = 0; c0 < 512; c0 += 4) {
        float4 wv[4];
        #pragma unroll
        for (int r = 0; r < 4; ++r) wv[r] = *(const float4*)&W5[(size_t)(t + 256 * r) * 512 + c0];
        #pragma unroll
        for (int pt = 0; pt < PTS; ++pt) {
            float4 cv = *(const float4*)&cat[pt][c0];
            #pragma unroll
            for (int r = 0; r < 4; ++r) {
                acc[r][pt] = fmaf(wv[r].x, cv.x, acc[r][pt]);
                acc[r][pt] = fmaf(wv[r].y, cv.y, acc[r][pt]);
                acc[r][pt] = fmaf(wv[r].z, cv.z, acc[r][pt]);
                acc[r][pt] = fmaf(wv[r].w, cv.w, acc[r][pt]);
            }
        }
    }
    #pragma unroll
    for (int r = 0; r < 4; ++r) {
        int o = t + 256 * r;
        float sv = s5[o], bv = b5[o];
        float mx = -INFINITY, sm = 0.f;
        #pragma unroll
        for (int pt = 0; pt < PTS; ++pt) {
            float v = lrelu(fmaf(acc[r][pt], sv, bv));
            mx = fmaxf(mx, v);
            sm += v;
        }
        atomicMax(&gmax[b * 1024 + o], fenc(mx));
        atomicAdd(&gsum[b * 1024 + o], sm);
    }
}

// g0[b, 0:1024] = decoded max ; g0[b, 1024:2048] = sum/N
__global__ __launch_bounds__(256) void k_poolfin(const unsigned* __restrict__ gmax, const float* __restrict__ gsum,
                                                 float* __restrict__ g0) {
    int i = blockIdx.x * 256 + threadIdx.x;  // B*1024
    int b = i >> 10, o = i & 1023;
    g0[(size_t)b * 2048 + o] = fdec(gmax[i]);
    g0[(size_t)b * 2048 + 1024 + o] = gsum[i] * (1.f / Np);
}

// Generic FC: out[b,o] = act((dot(In[b,:C], W[o,:]) + bias) * s + bnb). One wave per output.
__global__ __launch_bounds__(256) void k_fc(const float* __restrict__ In, int ldIn, int C,
                                            const float* __restrict__ Wm,
                                            const float* __restrict__ bias,
                                            const float* __restrict__ sc, const float* __restrict__ bnb,
                                            int leaky, float* __restrict__ Out, int ldOut, int O) {
    int wid = threadIdx.x >> 6, lane = threadIdx.x & 63;
    int o = blockIdx.x * 4 + wid;
    int b = blockIdx.y;
    if (o >= O) return;
    const float* in = In + (size_t)b * ldIn;
    const float* wr = Wm + (size_t)o * C;
    float acc = 0.f;
    for (int c = lane; c < C; c += 64) acc = fmaf(in[c], wr[c], acc);
    #pragma unroll
    for (int off = 32; off; off >>= 1) acc += __shfl_down(acc, off, 64);
    if (lane == 0) {
        float v = acc + (bias ? bias[o] : 0.f);
        if (sc) v = fmaf(v, sc[o], bnb[o]);
        if (leaky) v = lrelu(v);
        Out[(size_t)b * ldOut + o] = v;
    }
}

extern "C" void kernel_launch(void* const* d_in, const int* in_sizes, int n_in,
                              void* d_out, int out_size, void* d_ws, size_t ws_size,
                              hipStream_t stream) {
    const float* x   = (const float*)d_in[0];
    const float* W1  = (const float*)d_in[1];
    const float* s1  = (const float*)d_in[2];
    const float* b1  = (const float*)d_in[3];
    const float* W2  = (const float*)d_in[4];
    const float* s2  = (const float*)d_in[5];
    const float* b2  = (const float*)d_in[6];
    const float* W3  = (const float*)d_in[7];
    const float* s3  = (const float*)d_in[8];
    const float* b3  = (const float*)d_in[9];
    const float* W4  = (const float*)d_in[10];
    const float* s4  = (const float*)d_in[11];
    const float* b4  = (const float*)d_in[12];
    const float* W5  = (const float*)d_in[13];
    const float* s5  = (const float*)d_in[14];
    const float* b5  = (const float*)d_in[15];
    const float* L1w = (const float*)d_in[16];
    const float* s6  = (const float*)d_in[17];
    const float* b6  = (const float*)d_in[18];
    const float* L2w = (const float*)d_in[19];
    const float* L2b = (const float*)d_in[20];
    const float* s7  = (const float*)d_in[21];
    const float* b7  = (const float*)d_in[22];
    const float* L3w = (const float*)d_in[23];
    const float* L3b = (const float*)d_in[24];
    const float* F1w = (const float*)d_in[25];
    const float* s8  = (const float*)d_in[26];
    const float* b8  = (const float*)d_in[27];
    const float* F2w = (const float*)d_in[28];
    const float* F2b = (const float*)d_in[29];
    const float* s9  = (const float*)d_in[30];
    const float* b9  = (const float*)d_in[31];
    const float* F3w = (const float*)d_in[32];
    const float* F3b = (const float*)d_in[33];

    float* ws = (float*)d_ws;
    size_t off = 0;
    auto alloc = [&](size_t n) { float* p = ws + off; off += n; return p; };
    float* pts  = alloc((size_t)Bn * Np * 4);
    float* x1   = alloc((size_t)Bn * Np * 64);
    float* x2   = alloc((size_t)Bn * Np * 64);
    float* x3   = alloc((size_t)Bn * Np * 128);
    float* x4   = alloc((size_t)Bn * Np * 256);
    float* xcm  = alloc((size_t)Bn * Np * 128);
    float* xxb  = alloc((size_t)Bn * Np);
    int*   idxb = (int*)alloc((size_t)Bn * Np * Kn);
    unsigned* gmax = (unsigned*)alloc((size_t)Bn * 1024);
    float* gsum = alloc((size_t)Bn * 1024);
    float* g0   = alloc((size_t)Bn * 2048);
    float* g1   = alloc((size_t)Bn * 512);
    float* g2   = alloc((size_t)Bn * 256);
    float* y1   = alloc((size_t)Bn * 512);
    float* y2   = alloc((size_t)Bn * 256);

    hipMemsetAsync(gmax, 0, (size_t)Bn * 1024 * 2 * sizeof(float), stream);

    k_transpose<<<Bn * Np / 256, 256, 0, stream>>>(x, pts);

    // Layer 1: C=3 (cm = input x directly)
    k_xx<<<Bn * Np / 4, 256, 0, stream>>>(pts, xxb, 3, 4);
    k_knn<3><<<Bn * Np / 4, 256, 0, stream>>>(x, pts, 4, xxb, idxb);
    k_edgeconv<3, 4, 64, 1, 8, 1, true><<<Bn * Np, 256, 0, stream>>>(pts, idxb, W1, s1, b1, x1, xcm);

    // Layer 2: C=64 -> O=64
    k_xx<<<Bn * Np / 4, 256, 0, stream>>>(x1, xxb, 64, 64);
    k_knn<64><<<Bn * Np / 4, 256, 0, stream>>>(xcm, x1, 64, xxb, idxb);
    k_edgeconv<64, 64, 64, 2, 4, 2, true><<<Bn * Np / 2, 256, 0, stream>>>(x1, idxb, W2, s2, b2, x2, xcm);

    // Layer 3: C=64 -> O=128
    k_xx<<<Bn * Np / 4, 256, 0, stream>>>(x2, xxb, 64, 64);
    k_knn<64><<<Bn * Np / 4, 256, 0, stream>>>(xcm, x2, 64, xxb, idxb);
    k_edgeconv<64, 64, 128, 2, 8, 2, true><<<Bn * Np / 2, 256, 0, stream>>>(x2, idxb, W3, s3, b3, x3, xcm);

    // Layer 4: C=128 -> O=256 (no cm needed afterwards)
    k_xx<<<Bn * Np / 4, 256, 0, stream>>>(x3, xxb, 128, 128);
    k_knn<128><<<Bn * Np / 4, 256, 0, stream>>>(xcm, x3, 128, xxb, idxb);
    k_edgeconv<128, 128, 256, 2, 16, 2, false><<<Bn * Np / 2, 256, 0, stream>>>(x3, idxb, W4, s4, b4, x4, nullptr);

    // W5 + pooling
    k_w5pool<<<Bn * Np / 8, 256, 0, stream>>>(x1, x2, x3, x4, W5, s5, b5, gmax, gsum);
    k_poolfin<<<Bn * 1024 / 256, 256, 0, stream>>>(gmax, gsum, g0);

    float* out = (float*)d_out;
    // g branch (output 0)
    k_fc<<<dim3(128, Bn), 256, 0, stream>>>(g0, 2048, 2048, L1w, nullptr, s6, b6, 1, g1, 512, 512);
    k_fc<<<dim3(64, Bn), 256, 0, stream>>>(g1, 512, 512, L2w, L2b, s7, b7, 1, g2, 256, 256);
    k_fc<<<dim3(2, Bn), 256, 0, stream>>>(g2, 256, 256, L3w, L3b, nullptr, nullptr, 0, out, 5, 5);
    // y branch (output 1) — uses max half of g0
    k_fc<<<dim3(128, Bn), 256, 0, stream>>>(g0, 2048, 1024, F1w, nullptr, s8, b8, 1, y1, 512, 512);
    k_fc<<<dim3(64, Bn), 256, 0, stream>>>(y1, 512, 512, F2w, F2b, s9, b9, 1, y2, 256, 256);
    k_fc<<<dim3(2, Bn), 256, 0, stream>>>(y2, 256, 256, F3w, F3b, nullptr, nullptr, 0, out + 40, 5, 5);
}